// Round 1
// baseline (3699.868 us; speedup 1.0000x reference)
//
#include <hip/hip_runtime.h>
#include <hip/hip_bf16.h>

#define NN 100000
#define EE 800000
#define HEADS 8
#define ODIM 32
#define DALL 256
#define NEG 0.2f

// ---------------- GEMM: C[M,256] = A[M,256] @ W[256,256] + b ----------------
// 64x256 tile per block, 256 threads, 8x8 micro-tile per thread.
__global__ __launch_bounds__(256) void gemm256(const float* __restrict__ A,
                                               const float* __restrict__ W,
                                               const float* __restrict__ bvec,
                                               float* __restrict__ C, int M)
{
    __shared__ float As[64][33];   // 64 rows x 32 k (padded)
    __shared__ float Bs[32][256];  // 32 k x 256 cols

    const int t  = threadIdx.x;
    const int tx = t & 31;   // column group: cols {tx, tx+32, ..., tx+224}
    const int ty = t >> 5;   // row group: rows ty*8 .. ty*8+7
    const int rowBase = blockIdx.x * 64;

    float acc[8][8];
#pragma unroll
    for (int i = 0; i < 8; ++i)
#pragma unroll
        for (int j = 0; j < 8; ++j) acc[i][j] = 0.0f;

    for (int kb = 0; kb < 256; kb += 32) {
        // stage A tile: 64x32 floats = 512 float4; 2 per thread
#pragma unroll
        for (int i = 0; i < 2; ++i) {
            int lin  = t * 2 + i;          // float4 index
            int row  = lin >> 3;           // 8 float4 per row
            int kk4  = (lin & 7) * 4;
            int grow = rowBase + row;
            float4 v = make_float4(0.f, 0.f, 0.f, 0.f);
            if (grow < M)
                v = *reinterpret_cast<const float4*>(A + (size_t)grow * 256 + kb + kk4);
            As[row][kk4 + 0] = v.x; As[row][kk4 + 1] = v.y;
            As[row][kk4 + 2] = v.z; As[row][kk4 + 3] = v.w;
        }
        // stage B tile: 32x256 floats = 2048 float4; 8 per thread
#pragma unroll
        for (int i = 0; i < 8; ++i) {
            int lin = t + i * 256;         // float4 index, 64 float4 per B row
            int br_ = lin >> 6;
            int bc4 = (lin & 63) * 4;
            float4 v = *reinterpret_cast<const float4*>(W + (size_t)(kb + br_) * 256 + bc4);
            *reinterpret_cast<float4*>(&Bs[br_][bc4]) = v;
        }
        __syncthreads();
#pragma unroll
        for (int kk = 0; kk < 32; ++kk) {
            float a[8], bb[8];
#pragma unroll
            for (int i = 0; i < 8; ++i) a[i] = As[ty * 8 + i][kk];
#pragma unroll
            for (int j = 0; j < 8; ++j) bb[j] = Bs[kk][tx + 32 * j];
#pragma unroll
            for (int i = 0; i < 8; ++i)
#pragma unroll
                for (int j = 0; j < 8; ++j) acc[i][j] += a[i] * bb[j];
        }
        __syncthreads();
    }
#pragma unroll
    for (int i = 0; i < 8; ++i) {
        int grow = rowBase + ty * 8 + i;
        if (grow < M) {
#pragma unroll
            for (int j = 0; j < 8; ++j) {
                int col = tx + 32 * j;
                C[(size_t)grow * 256 + col] = acc[i][j] + bvec[col];
            }
        }
    }
}

// ---------------- edge score: p = exp(a^T lrelu(xl[src]+xr[dst])), denom += p
__global__ __launch_bounds__(256) void edge_score(const float* __restrict__ xl,
                                                  const float* __restrict__ xr,
                                                  const int* __restrict__ src,
                                                  const int* __restrict__ dst,
                                                  const float* __restrict__ att,
                                                  float* __restrict__ p,
                                                  float* __restrict__ denom)
{
    int e = blockIdx.x * 4 + (threadIdx.x >> 6);
    if (e >= EE) return;
    int lane = threadIdx.x & 63;
    int s = src[e], d = dst[e];

    float4 a  = *reinterpret_cast<const float4*>(xl + (size_t)s * DALL + lane * 4);
    float4 b  = *reinterpret_cast<const float4*>(xr + (size_t)d * DALL + lane * 4);
    float4 at = *reinterpret_cast<const float4*>(att + lane * 4);  // [h][d] layout == lane*4

    float tx0 = a.x + b.x, tx1 = a.y + b.y, tx2 = a.z + b.z, tx3 = a.w + b.w;
    tx0 = tx0 > 0.f ? tx0 : NEG * tx0;
    tx1 = tx1 > 0.f ? tx1 : NEG * tx1;
    tx2 = tx2 > 0.f ? tx2 : NEG * tx2;
    tx3 = tx3 > 0.f ? tx3 : NEG * tx3;
    float partial = tx0 * at.x + tx1 * at.y + tx2 * at.z + tx3 * at.w;

    // reduce across the 8 lanes of this head
    partial += __shfl_xor(partial, 1);
    partial += __shfl_xor(partial, 2);
    partial += __shfl_xor(partial, 4);

    if ((lane & 7) == 0) {
        int h = lane >> 3;
        float pe = expf(partial);
        p[(size_t)e * HEADS + h] = pe;
        atomicAdd(&denom[(size_t)d * HEADS + h], pe);
    }
}

// ---------------- aggregate: out[dst] += (p/denom[dst]) * xl[src] ----------
__global__ __launch_bounds__(256) void edge_aggregate(const float* __restrict__ xl,
                                                      const float* __restrict__ p,
                                                      const float* __restrict__ denom,
                                                      const int* __restrict__ src,
                                                      const int* __restrict__ dst,
                                                      float* __restrict__ out)
{
    int e = blockIdx.x * 4 + (threadIdx.x >> 6);
    if (e >= EE) return;
    int lane = threadIdx.x & 63;
    int s = src[e], d = dst[e];
    int h = lane >> 3;

    float alpha = p[(size_t)e * HEADS + h] / denom[(size_t)d * HEADS + h];
    float4 v = *reinterpret_cast<const float4*>(xl + (size_t)s * DALL + lane * 4);
    float* o = out + (size_t)d * DALL + lane * 4;
    atomicAdd(o + 0, alpha * v.x);
    atomicAdd(o + 1, alpha * v.y);
    atomicAdd(o + 2, alpha * v.z);
    atomicAdd(o + 3, alpha * v.w);
}

// ---------------- finalize: out = elu(LN(out + bias + x)*gamma + beta) -----
__global__ __launch_bounds__(256) void finalize(const float* __restrict__ x,
                                                const float* __restrict__ bias,
                                                const float* __restrict__ gamma,
                                                const float* __restrict__ beta,
                                                float* __restrict__ out)
{
    int node = blockIdx.x * 4 + (threadIdx.x >> 6);
    if (node >= NN) return;
    int lane = threadIdx.x & 63;

    float4 y  = *reinterpret_cast<const float4*>(out + (size_t)node * DALL + lane * 4);
    float4 xv = *reinterpret_cast<const float4*>(x + (size_t)node * DALL + lane * 4);
    float4 bv = *reinterpret_cast<const float4*>(bias + lane * 4);
    y.x += xv.x + bv.x; y.y += xv.y + bv.y; y.z += xv.z + bv.z; y.w += xv.w + bv.w;

    float sum = y.x + y.y + y.z + y.w;
    float sq  = y.x * y.x + y.y * y.y + y.z * y.z + y.w * y.w;
#pragma unroll
    for (int m = 1; m < 64; m <<= 1) {
        sum += __shfl_xor(sum, m);
        sq  += __shfl_xor(sq, m);
    }
    float mu  = sum * (1.0f / 256.0f);
    float var = sq * (1.0f / 256.0f) - mu * mu;
    float r   = rsqrtf(var + 1e-5f);

    float4 gv = *reinterpret_cast<const float4*>(gamma + lane * 4);
    float4 be = *reinterpret_cast<const float4*>(beta + lane * 4);
    float z0 = (y.x - mu) * r * gv.x + be.x;
    float z1 = (y.y - mu) * r * gv.y + be.y;
    float z2 = (y.z - mu) * r * gv.z + be.z;
    float z3 = (y.w - mu) * r * gv.w + be.w;
    y.x = z0 > 0.f ? z0 : expm1f(z0);
    y.y = z1 > 0.f ? z1 : expm1f(z1);
    y.z = z2 > 0.f ? z2 : expm1f(z2);
    y.w = z3 > 0.f ? z3 : expm1f(z3);
    *reinterpret_cast<float4*>(out + (size_t)node * DALL + lane * 4) = y;
}

extern "C" void kernel_launch(void* const* d_in, const int* in_sizes, int n_in,
                              void* d_out, int out_size, void* d_ws, size_t ws_size,
                              hipStream_t stream)
{
    const float* x    = (const float*)d_in[0];
    const int*   edge = (const int*)d_in[1];     // [2][E]
    const float* Wl   = (const float*)d_in[2];
    const float* bl   = (const float*)d_in[3];
    const float* Wr   = (const float*)d_in[4];
    const float* br   = (const float*)d_in[5];
    const float* att  = (const float*)d_in[6];
    const float* bias = (const float*)d_in[7];
    const float* gamma= (const float*)d_in[8];
    const float* beta = (const float*)d_in[9];
    float* out = (float*)d_out;

    const int* srcIdx = edge;
    const int* dstIdx = edge + EE;

    float* xl    = (float*)d_ws;                        // N*256
    float* xr    = xl + (size_t)NN * DALL;              // N*256
    float* pbuf  = xr + (size_t)NN * DALL;              // E*8
    float* denom = pbuf + (size_t)EE * HEADS;           // N*8

    hipMemsetAsync(d_out, 0, (size_t)NN * DALL * sizeof(float), stream);
    hipMemsetAsync(denom, 0, (size_t)NN * HEADS * sizeof(float), stream);

    gemm256<<<(NN + 63) / 64, 256, 0, stream>>>(x, Wl, bl, xl, NN);
    gemm256<<<(NN + 63) / 64, 256, 0, stream>>>(x, Wr, br, xr, NN);
    edge_score<<<EE / 4, 256, 0, stream>>>(xl, xr, srcIdx, dstIdx, att, pbuf, denom);
    edge_aggregate<<<EE / 4, 256, 0, stream>>>(xl, pbuf, denom, srcIdx, dstIdx, out);
    finalize<<<NN / 4, 256, 0, stream>>>(x, bias, gamma, beta, out);
}

// Round 2
// 1030.227 us; speedup vs baseline: 3.5913x; 3.5913x over previous
//
#include <hip/hip_runtime.h>
#include <hip/hip_bf16.h>

#define NN 100000
#define EE 800000
#define HEADS 8
#define DALL 256
#define NEG 0.2f

// ---------------- GEMM: C[M,256] = A[M,256] @ W[256,256] + b ----------------
__global__ __launch_bounds__(256) void gemm256(const float* __restrict__ A,
                                               const float* __restrict__ W,
                                               const float* __restrict__ bvec,
                                               float* __restrict__ C, int M)
{
    __shared__ float As[64][33];
    __shared__ float Bs[32][256];

    const int t  = threadIdx.x;
    const int tx = t & 31;
    const int ty = t >> 5;
    const int rowBase = blockIdx.x * 64;

    float acc[8][8];
#pragma unroll
    for (int i = 0; i < 8; ++i)
#pragma unroll
        for (int j = 0; j < 8; ++j) acc[i][j] = 0.0f;

    for (int kb = 0; kb < 256; kb += 32) {
#pragma unroll
        for (int i = 0; i < 2; ++i) {
            int lin  = t * 2 + i;
            int row  = lin >> 3;
            int kk4  = (lin & 7) * 4;
            int grow = rowBase + row;
            float4 v = make_float4(0.f, 0.f, 0.f, 0.f);
            if (grow < M)
                v = *reinterpret_cast<const float4*>(A + (size_t)grow * 256 + kb + kk4);
            As[row][kk4 + 0] = v.x; As[row][kk4 + 1] = v.y;
            As[row][kk4 + 2] = v.z; As[row][kk4 + 3] = v.w;
        }
#pragma unroll
        for (int i = 0; i < 8; ++i) {
            int lin = t + i * 256;
            int br_ = lin >> 6;
            int bc4 = (lin & 63) * 4;
            float4 v = *reinterpret_cast<const float4*>(W + (size_t)(kb + br_) * 256 + bc4);
            *reinterpret_cast<float4*>(&Bs[br_][bc4]) = v;
        }
        __syncthreads();
#pragma unroll
        for (int kk = 0; kk < 32; ++kk) {
            float a[8], bb[8];
#pragma unroll
            for (int i = 0; i < 8; ++i) a[i] = As[ty * 8 + i][kk];
#pragma unroll
            for (int j = 0; j < 8; ++j) bb[j] = Bs[kk][tx + 32 * j];
#pragma unroll
            for (int i = 0; i < 8; ++i)
#pragma unroll
                for (int j = 0; j < 8; ++j) acc[i][j] += a[i] * bb[j];
        }
        __syncthreads();
    }
#pragma unroll
    for (int i = 0; i < 8; ++i) {
        int grow = rowBase + ty * 8 + i;
        if (grow < M) {
#pragma unroll
            for (int j = 0; j < 8; ++j) {
                int col = tx + 32 * j;
                C[(size_t)grow * 256 + col] = acc[i][j] + bvec[col];
            }
        }
    }
}

// ---------------- CSR build ------------------------------------------------
__global__ __launch_bounds__(256) void count_deg(const int* __restrict__ dst,
                                                 int* __restrict__ cnt)
{
    int e = blockIdx.x * 256 + threadIdx.x;
    if (e < EE) atomicAdd(&cnt[dst[e]], 1);
}

// exclusive scan of cnt[NN] -> rowptr[NN], rowptr[NN]=E. 1024 elems/block.
__global__ __launch_bounds__(256) void scan_part1(const int* __restrict__ cnt,
                                                  int* __restrict__ bsums)
{
    __shared__ int red[256];
    int base = blockIdx.x * 1024 + threadIdx.x * 4;
    int s = 0;
#pragma unroll
    for (int k = 0; k < 4; ++k) { int i = base + k; if (i < NN) s += cnt[i]; }
    red[threadIdx.x] = s; __syncthreads();
    for (int off = 128; off > 0; off >>= 1) {
        if (threadIdx.x < off) red[threadIdx.x] += red[threadIdx.x + off];
        __syncthreads();
    }
    if (threadIdx.x == 0) bsums[blockIdx.x] = red[0];
}

__global__ void scan_part2(int* bsums, int nb, int* rowptr)
{
    if (threadIdx.x == 0 && blockIdx.x == 0) {
        int run = 0;
        for (int i = 0; i < nb; ++i) { int v = bsums[i]; bsums[i] = run; run += v; }
        rowptr[NN] = run;
    }
}

__global__ __launch_bounds__(256) void scan_part3(const int* __restrict__ cnt,
                                                  const int* __restrict__ bsums,
                                                  int* __restrict__ rowptr)
{
    __shared__ int pre[256];
    int base = blockIdx.x * 1024 + threadIdx.x * 4;
    int v[4]; int s = 0;
#pragma unroll
    for (int k = 0; k < 4; ++k) { int i = base + k; v[k] = (i < NN) ? cnt[i] : 0; s += v[k]; }
    pre[threadIdx.x] = s; __syncthreads();
    for (int off = 1; off < 256; off <<= 1) {
        int t = (threadIdx.x >= off) ? pre[threadIdx.x - off] : 0;
        __syncthreads();
        pre[threadIdx.x] += t;
        __syncthreads();
    }
    int excl = pre[threadIdx.x] - s + bsums[blockIdx.x];
#pragma unroll
    for (int k = 0; k < 4; ++k) {
        int i = base + k;
        if (i < NN) { rowptr[i] = excl; excl += v[k]; }
    }
}

__global__ __launch_bounds__(256) void fill_csr(const int* __restrict__ dst,
                                                const int* __restrict__ rowptr,
                                                int* __restrict__ cursor,
                                                int* __restrict__ eid)
{
    int e = blockIdx.x * 256 + threadIdx.x;
    if (e >= EE) return;
    int d = dst[e];
    int pos = atomicAdd(&cursor[d], 1);
    eid[rowptr[d] + pos] = e;
}

// ------------- fused: score + softmax-agg + bias + residual + LN + ELU -----
// one wave64 per node; lane covers dims [lane*4, lane*4+4), head = lane>>3
__global__ __launch_bounds__(256) void aggregate_finalize(
    const float* __restrict__ xl, const float* __restrict__ xr,
    const int* __restrict__ src, const int* __restrict__ rowptr,
    const int* __restrict__ eid, const float* __restrict__ att,
    const float* __restrict__ x, const float* __restrict__ bias,
    const float* __restrict__ gamma, const float* __restrict__ beta,
    float* __restrict__ out)
{
    int node = blockIdx.x * 4 + (threadIdx.x >> 6);
    if (node >= NN) return;
    int lane = threadIdx.x & 63;

    float4 xrv = *reinterpret_cast<const float4*>(xr + (size_t)node * DALL + lane * 4);
    float4 atv = *reinterpret_cast<const float4*>(att + lane * 4);

    int beg = rowptr[node], end = rowptr[node + 1];
    float a0 = 0.f, a1 = 0.f, a2 = 0.f, a3 = 0.f, dsum = 0.f;

    for (int j = beg; j < end; ++j) {
        int e = eid[j];
        int s = src[e];
        float4 v = *reinterpret_cast<const float4*>(xl + (size_t)s * DALL + lane * 4);
        float z0 = v.x + xrv.x, z1 = v.y + xrv.y, z2 = v.z + xrv.z, z3 = v.w + xrv.w;
        z0 = fmaxf(z0, 0.f) + NEG * fminf(z0, 0.f);
        z1 = fmaxf(z1, 0.f) + NEG * fminf(z1, 0.f);
        z2 = fmaxf(z2, 0.f) + NEG * fminf(z2, 0.f);
        z3 = fmaxf(z3, 0.f) + NEG * fminf(z3, 0.f);
        float sc = z0 * atv.x + z1 * atv.y + z2 * atv.z + z3 * atv.w;
        sc += __shfl_xor(sc, 1);
        sc += __shfl_xor(sc, 2);
        sc += __shfl_xor(sc, 4);          // all 8 lanes of head hold full score
        float pe = __expf(sc);
        a0 += pe * v.x; a1 += pe * v.y; a2 += pe * v.z; a3 += pe * v.w;
        dsum += pe;
    }

    float inv = dsum > 0.f ? 1.f / dsum : 0.f;

    float4 xv = *reinterpret_cast<const float4*>(x + (size_t)node * DALL + lane * 4);
    float4 bv = *reinterpret_cast<const float4*>(bias + lane * 4);
    float y0 = a0 * inv + bv.x + xv.x;
    float y1 = a1 * inv + bv.y + xv.y;
    float y2 = a2 * inv + bv.z + xv.z;
    float y3 = a3 * inv + bv.w + xv.w;

    float sum = y0 + y1 + y2 + y3;
    float sq  = y0 * y0 + y1 * y1 + y2 * y2 + y3 * y3;
#pragma unroll
    for (int m = 1; m < 64; m <<= 1) {
        sum += __shfl_xor(sum, m);
        sq  += __shfl_xor(sq, m);
    }
    float mu  = sum * (1.0f / 256.0f);
    float var = sq * (1.0f / 256.0f) - mu * mu;
    float r   = rsqrtf(var + 1e-5f);

    float4 gv = *reinterpret_cast<const float4*>(gamma + lane * 4);
    float4 be = *reinterpret_cast<const float4*>(beta + lane * 4);
    float z0 = (y0 - mu) * r * gv.x + be.x;
    float z1 = (y1 - mu) * r * gv.y + be.y;
    float z2 = (y2 - mu) * r * gv.z + be.z;
    float z3 = (y3 - mu) * r * gv.w + be.w;
    float4 o;
    o.x = z0 > 0.f ? z0 : expm1f(z0);
    o.y = z1 > 0.f ? z1 : expm1f(z1);
    o.z = z2 > 0.f ? z2 : expm1f(z2);
    o.w = z3 > 0.f ? z3 : expm1f(z3);
    *reinterpret_cast<float4*>(out + (size_t)node * DALL + lane * 4) = o;
}

extern "C" void kernel_launch(void* const* d_in, const int* in_sizes, int n_in,
                              void* d_out, int out_size, void* d_ws, size_t ws_size,
                              hipStream_t stream)
{
    const float* x    = (const float*)d_in[0];
    const int*   edge = (const int*)d_in[1];     // [2][E]
    const float* Wl   = (const float*)d_in[2];
    const float* bl   = (const float*)d_in[3];
    const float* Wr   = (const float*)d_in[4];
    const float* br   = (const float*)d_in[5];
    const float* att  = (const float*)d_in[6];
    const float* bias = (const float*)d_in[7];
    const float* gamma= (const float*)d_in[8];
    const float* beta = (const float*)d_in[9];
    float* out = (float*)d_out;

    const int* srcIdx = edge;
    const int* dstIdx = edge + EE;

    float* xl = (float*)d_ws;                       // N*256
    float* xr = xl + (size_t)NN * DALL;             // N*256
    int* rowptr = (int*)(xr + (size_t)NN * DALL);   // NN+1
    int* cursor = rowptr + NN + 1;                  // NN (also deg counts)
    int* eid    = cursor + NN;                      // EE
    int* bsums  = eid + EE;                         // 128

    const int SCAN_NB = (NN + 1023) / 1024;         // 98

    gemm256<<<(NN + 63) / 64, 256, 0, stream>>>(x, Wl, bl, xl, NN);
    gemm256<<<(NN + 63) / 64, 256, 0, stream>>>(x, Wr, br, xr, NN);

    hipMemsetAsync(cursor, 0, NN * sizeof(int), stream);
    count_deg<<<(EE + 255) / 256, 256, 0, stream>>>(dstIdx, cursor);
    scan_part1<<<SCAN_NB, 256, 0, stream>>>(cursor, bsums);
    scan_part2<<<1, 64, 0, stream>>>(bsums, SCAN_NB, rowptr);
    scan_part3<<<SCAN_NB, 256, 0, stream>>>(cursor, bsums, rowptr);
    hipMemsetAsync(cursor, 0, NN * sizeof(int), stream);
    fill_csr<<<(EE + 255) / 256, 256, 0, stream>>>(dstIdx, rowptr, cursor, eid);

    aggregate_finalize<<<(NN + 3) / 4, 256, 0, stream>>>(
        xl, xr, srcIdx, rowptr, eid, att, x, bias, gamma, beta, out);
}

// Round 3
// 450.889 us; speedup vs baseline: 8.2057x; 2.2849x over previous
//
#include <hip/hip_runtime.h>
#include <hip/hip_bf16.h>

#define NN 100000
#define EE 800000
#define HEADS 8
#define DALL 256
#define NEG 0.2f
#define PITCH 80   // LDS row pitch in bytes: 32 bf16 (64B) + 16B pad

typedef __attribute__((ext_vector_type(8))) short bf16x8;
typedef __attribute__((ext_vector_type(4))) float f32x4;

static __device__ __forceinline__ ushort f2b(float f) {
    __hip_bfloat16 h = __float2bfloat16(f);
    return *reinterpret_cast<ushort*>(&h);
}
static __device__ __forceinline__ float b2f(ushort u) {
    union { float f; unsigned v; } c; c.v = ((unsigned)u) << 16; return c.f;
}

// ---------------- convert x (fp32 -> bf16), 8 elems/thread/iter ------------
__global__ __launch_bounds__(256) void cvt_x(const float* __restrict__ in,
                                             ushort* __restrict__ out)
{
    const int total = NN * DALL / 8;
    for (int i = blockIdx.x * 256 + threadIdx.x; i < total; i += gridDim.x * 256) {
        float4 a = reinterpret_cast<const float4*>(in)[i * 2];
        float4 b = reinterpret_cast<const float4*>(in)[i * 2 + 1];
        uint4 o;
        o.x = f2b(a.x) | ((unsigned)f2b(a.y) << 16);
        o.y = f2b(a.z) | ((unsigned)f2b(a.w) << 16);
        o.z = f2b(b.x) | ((unsigned)f2b(b.y) << 16);
        o.w = f2b(b.z) | ((unsigned)f2b(b.w) << 16);
        reinterpret_cast<uint4*>(out)[i] = o;
    }
}

// ------- build Wt[n][k] = bf16 of (n<256 ? Wl[k][n] : Wr[k][n-256]) --------
__global__ __launch_bounds__(256) void cvt_W(const float* __restrict__ Wl,
                                             const float* __restrict__ Wr,
                                             ushort* __restrict__ Wt)
{
    __shared__ float tile[32][33];
    int kt = blockIdx.x * 32, nt = blockIdx.y * 32;
    int tx = threadIdx.x & 31, ty = threadIdx.x >> 5;
#pragma unroll
    for (int i = 0; i < 32; i += 8) {
        int k = kt + ty + i, n = nt + tx;
        float v = (n < 256) ? Wl[(size_t)k * 256 + n] : Wr[(size_t)k * 256 + (n - 256)];
        tile[ty + i][tx] = v;
    }
    __syncthreads();
#pragma unroll
    for (int i = 0; i < 32; i += 8) {
        int n = nt + ty + i, k = kt + tx;
        Wt[(size_t)n * 256 + k] = f2b(tile[tx][ty + i]);
    }
}

// ---------------- MFMA GEMM: [xl|xr] = xb @ Wt^T + [bl|br] -----------------
// block: 128 rows x 128 cols, 4 waves (2x2), 64x64 per wave, K-step 32, dbuf
__global__ __launch_bounds__(256) void gemm_dual(
    const ushort* __restrict__ xb,   // [NN][256] bf16
    const ushort* __restrict__ Wt,   // [512][256] bf16 (col-major B)
    const float* __restrict__ bl, const float* __restrict__ br,
    ushort* __restrict__ xl, ushort* __restrict__ xr)
{
    __shared__ __align__(16) unsigned char smem[2][2][128 * PITCH]; // [buf][A,B]

    const int bx = blockIdx.x;
    const int rowBase = (bx >> 2) * 128;
    const int colBase = (bx & 3) * 128;
    const int t = threadIdx.x, lane = t & 63, wave = t >> 6;
    const int wr = (wave >> 1) * 64, wc = (wave & 1) * 64;

    f32x4 acc[4][4];
#pragma unroll
    for (int m = 0; m < 4; ++m)
#pragma unroll
        for (int n = 0; n < 4; ++n) acc[m][n] = (f32x4){0.f, 0.f, 0.f, 0.f};

    uint4 ra[2], rb[2];

    auto LOAD = [&](int kb) {
#pragma unroll
        for (int i = 0; i < 2; ++i) {
            int c = t + i * 256;
            int rc = c >> 2, slot = c & 3;
            int g = rowBase + rc; if (g >= NN) g = NN - 1;
            ra[i] = *reinterpret_cast<const uint4*>(xb + (size_t)g * 256 + kb + slot * 8);
            rb[i] = *reinterpret_cast<const uint4*>(Wt + (size_t)(colBase + rc) * 256 + kb + slot * 8);
        }
    };
    auto WRITE = [&](int buf) {
#pragma unroll
        for (int i = 0; i < 2; ++i) {
            int c = t + i * 256;
            int rc = c >> 2, slot = c & 3;
            *reinterpret_cast<uint4*>(&smem[buf][0][rc * PITCH + slot * 16]) = ra[i];
            *reinterpret_cast<uint4*>(&smem[buf][1][rc * PITCH + slot * 16]) = rb[i];
        }
    };

    LOAD(0); WRITE(0); __syncthreads();

#pragma unroll
    for (int s = 0; s < 8; ++s) {
        if (s < 7) LOAD((s + 1) * 32);

        const unsigned char* A = smem[s & 1][0];
        const unsigned char* B = smem[s & 1][1];
        bf16x8 af[4], bfr[4];
#pragma unroll
        for (int m = 0; m < 4; ++m)
            af[m] = *reinterpret_cast<const bf16x8*>(
                A + (wr + m * 16 + (lane & 15)) * PITCH + (lane >> 4) * 16);
#pragma unroll
        for (int n = 0; n < 4; ++n)
            bfr[n] = *reinterpret_cast<const bf16x8*>(
                B + (wc + n * 16 + (lane & 15)) * PITCH + (lane >> 4) * 16);
#pragma unroll
        for (int m = 0; m < 4; ++m)
#pragma unroll
            for (int n = 0; n < 4; ++n)
                acc[m][n] = __builtin_amdgcn_mfma_f32_16x16x32_bf16(
                    af[m], bfr[n], acc[m][n], 0, 0, 0);

        if (s < 7) WRITE((s + 1) & 1);
        __syncthreads();
    }

    // epilogue
    const bool isL = (colBase < 256);
    ushort* OutP = isL ? xl : xr;
    const float* bvp = isL ? bl : br;
    const int cb0 = colBase & 255;

    int colLoc[4]; float bb[4];
#pragma unroll
    for (int n = 0; n < 4; ++n) {
        colLoc[n] = cb0 + wc + n * 16 + (lane & 15);
        bb[n] = bvp[colLoc[n]];
    }
#pragma unroll
    for (int m = 0; m < 4; ++m) {
        int r0 = rowBase + wr + m * 16 + (lane >> 4) * 4;
#pragma unroll
        for (int r = 0; r < 4; ++r) {
            int row = r0 + r;
            if (row < NN) {
#pragma unroll
                for (int n = 0; n < 4; ++n)
                    OutP[(size_t)row * 256 + colLoc[n]] = f2b(acc[m][n][r] + bb[n]);
            }
        }
    }
}

// ---------------- CSR build ------------------------------------------------
__global__ __launch_bounds__(256) void count_deg(const int* __restrict__ dst,
                                                 int* __restrict__ cnt)
{
    int e = blockIdx.x * 256 + threadIdx.x;
    if (e < EE) atomicAdd(&cnt[dst[e]], 1);
}

__global__ __launch_bounds__(256) void scan_part1(const int* __restrict__ cnt,
                                                  int* __restrict__ bsums)
{
    __shared__ int red[256];
    int base = blockIdx.x * 1024 + threadIdx.x * 4;
    int s = 0;
#pragma unroll
    for (int k = 0; k < 4; ++k) { int i = base + k; if (i < NN) s += cnt[i]; }
    red[threadIdx.x] = s; __syncthreads();
    for (int off = 128; off > 0; off >>= 1) {
        if (threadIdx.x < off) red[threadIdx.x] += red[threadIdx.x + off];
        __syncthreads();
    }
    if (threadIdx.x == 0) bsums[blockIdx.x] = red[0];
}

__global__ void scan_part2(int* bsums, int nb, int* rowptr)
{
    if (threadIdx.x == 0 && blockIdx.x == 0) {
        int run = 0;
        for (int i = 0; i < nb; ++i) { int v = bsums[i]; bsums[i] = run; run += v; }
        rowptr[NN] = run;
    }
}

__global__ __launch_bounds__(256) void scan_part3(const int* __restrict__ cnt,
                                                  const int* __restrict__ bsums,
                                                  int* __restrict__ rowptr)
{
    __shared__ int pre[256];
    int base = blockIdx.x * 1024 + threadIdx.x * 4;
    int v[4]; int s = 0;
#pragma unroll
    for (int k = 0; k < 4; ++k) { int i = base + k; v[k] = (i < NN) ? cnt[i] : 0; s += v[k]; }
    pre[threadIdx.x] = s; __syncthreads();
    for (int off = 1; off < 256; off <<= 1) {
        int tv = (threadIdx.x >= off) ? pre[threadIdx.x - off] : 0;
        __syncthreads();
        pre[threadIdx.x] += tv;
        __syncthreads();
    }
    int excl = pre[threadIdx.x] - s + bsums[blockIdx.x];
#pragma unroll
    for (int k = 0; k < 4; ++k) {
        int i = base + k;
        if (i < NN) { rowptr[i] = excl; excl += v[k]; }
    }
}

__global__ __launch_bounds__(256) void fill_csr(const int* __restrict__ dst,
                                                const int* __restrict__ rowptr,
                                                int* __restrict__ cursor,
                                                int* __restrict__ eid)
{
    int e = blockIdx.x * 256 + threadIdx.x;
    if (e >= EE) return;
    int d = dst[e];
    int pos = atomicAdd(&cursor[d], 1);
    eid[rowptr[d] + pos] = e;
}

// ------------- fused: score + softmax-agg + bias + residual + LN + ELU -----
__global__ __launch_bounds__(256) void aggregate_finalize(
    const ushort* __restrict__ xl, const ushort* __restrict__ xr,
    const int* __restrict__ src, const int* __restrict__ rowptr,
    const int* __restrict__ eid, const float* __restrict__ att,
    const float* __restrict__ x, const float* __restrict__ bias,
    const float* __restrict__ gamma, const float* __restrict__ beta,
    float* __restrict__ out)
{
    int node = blockIdx.x * 4 + (threadIdx.x >> 6);
    if (node >= NN) return;
    int lane = threadIdx.x & 63;

    ushort4 xru = *reinterpret_cast<const ushort4*>(xr + (size_t)node * DALL + lane * 4);
    float xr0 = b2f(xru.x), xr1 = b2f(xru.y), xr2 = b2f(xru.z), xr3 = b2f(xru.w);
    float4 atv = *reinterpret_cast<const float4*>(att + lane * 4);

    int beg = rowptr[node], end = rowptr[node + 1];
    float a0 = 0.f, a1 = 0.f, a2 = 0.f, a3 = 0.f, dsum = 0.f;

    for (int j = beg; j < end; ++j) {
        int e = eid[j];
        int s = src[e];
        ushort4 vu = *reinterpret_cast<const ushort4*>(xl + (size_t)s * DALL + lane * 4);
        float v0 = b2f(vu.x), v1 = b2f(vu.y), v2 = b2f(vu.z), v3 = b2f(vu.w);
        float z0 = v0 + xr0, z1 = v1 + xr1, z2 = v2 + xr2, z3 = v3 + xr3;
        z0 = fmaxf(z0, 0.f) + NEG * fminf(z0, 0.f);
        z1 = fmaxf(z1, 0.f) + NEG * fminf(z1, 0.f);
        z2 = fmaxf(z2, 0.f) + NEG * fminf(z2, 0.f);
        z3 = fmaxf(z3, 0.f) + NEG * fminf(z3, 0.f);
        float sc = z0 * atv.x + z1 * atv.y + z2 * atv.z + z3 * atv.w;
        sc += __shfl_xor(sc, 1);
        sc += __shfl_xor(sc, 2);
        sc += __shfl_xor(sc, 4);
        float pe = __expf(sc);
        a0 += pe * v0; a1 += pe * v1; a2 += pe * v2; a3 += pe * v3;
        dsum += pe;
    }

    float inv = dsum > 0.f ? 1.f / dsum : 0.f;

    float4 xv = *reinterpret_cast<const float4*>(x + (size_t)node * DALL + lane * 4);
    float4 bv = *reinterpret_cast<const float4*>(bias + lane * 4);
    float y0 = a0 * inv + bv.x + xv.x;
    float y1 = a1 * inv + bv.y + xv.y;
    float y2 = a2 * inv + bv.z + xv.z;
    float y3 = a3 * inv + bv.w + xv.w;

    float sum = y0 + y1 + y2 + y3;
    float sq  = y0 * y0 + y1 * y1 + y2 * y2 + y3 * y3;
#pragma unroll
    for (int m = 1; m < 64; m <<= 1) {
        sum += __shfl_xor(sum, m);
        sq  += __shfl_xor(sq, m);
    }
    float mu  = sum * (1.0f / 256.0f);
    float var = sq * (1.0f / 256.0f) - mu * mu;
    float r   = rsqrtf(var + 1e-5f);

    float4 gv = *reinterpret_cast<const float4*>(gamma + lane * 4);
    float4 be = *reinterpret_cast<const float4*>(beta + lane * 4);
    float z0 = (y0 - mu) * r * gv.x + be.x;
    float z1 = (y1 - mu) * r * gv.y + be.y;
    float z2 = (y2 - mu) * r * gv.z + be.z;
    float z3 = (y3 - mu) * r * gv.w + be.w;
    float4 o;
    o.x = z0 > 0.f ? z0 : expm1f(z0);
    o.y = z1 > 0.f ? z1 : expm1f(z1);
    o.z = z2 > 0.f ? z2 : expm1f(z2);
    o.w = z3 > 0.f ? z3 : expm1f(z3);
    *reinterpret_cast<float4*>(out + (size_t)node * DALL + lane * 4) = o;
}

extern "C" void kernel_launch(void* const* d_in, const int* in_sizes, int n_in,
                              void* d_out, int out_size, void* d_ws, size_t ws_size,
                              hipStream_t stream)
{
    const float* x    = (const float*)d_in[0];
    const int*   edge = (const int*)d_in[1];
    const float* Wl   = (const float*)d_in[2];
    const float* bl   = (const float*)d_in[3];
    const float* Wr   = (const float*)d_in[4];
    const float* br   = (const float*)d_in[5];
    const float* att  = (const float*)d_in[6];
    const float* bias = (const float*)d_in[7];
    const float* gamma= (const float*)d_in[8];
    const float* beta = (const float*)d_in[9];
    float* out = (float*)d_out;

    const int* srcIdx = edge;
    const int* dstIdx = edge + EE;

    ushort* xl = (ushort*)d_ws;                     // NN*256 bf16
    ushort* xr = xl + (size_t)NN * DALL;            // NN*256 bf16
    ushort* xb = xr + (size_t)NN * DALL;            // NN*256 bf16
    ushort* Wt = xb + (size_t)NN * DALL;            // 512*256 bf16
    int* rowptr = (int*)(Wt + 512 * 256);           // NN+1
    int* cursor = rowptr + NN + 1;                  // NN
    int* eid    = cursor + NN;                      // EE
    int* bsums  = eid + EE;                         // 128

    const int SCAN_NB = (NN + 1023) / 1024;

    cvt_x<<<2048, 256, 0, stream>>>(x, xb);
    cvt_W<<<dim3(8, 16), 256, 0, stream>>>(Wl, Wr, Wt);
    gemm_dual<<<782 * 4, 256, 0, stream>>>(xb, Wt, bl, br, xl, xr);

    hipMemsetAsync(cursor, 0, NN * sizeof(int), stream);
    count_deg<<<(EE + 255) / 256, 256, 0, stream>>>(dstIdx, cursor);
    scan_part1<<<SCAN_NB, 256, 0, stream>>>(cursor, bsums);
    scan_part2<<<1, 64, 0, stream>>>(bsums, SCAN_NB, rowptr);
    scan_part3<<<SCAN_NB, 256, 0, stream>>>(cursor, bsums, rowptr);
    hipMemsetAsync(cursor, 0, NN * sizeof(int), stream);
    fill_csr<<<(EE + 255) / 256, 256, 0, stream>>>(dstIdx, rowptr, cursor, eid);

    aggregate_finalize<<<NN / 4, 256, 0, stream>>>(
        xl, xr, srcIdx, rowptr, eid, att, x, bias, gamma, beta, out);
}

// Round 6
// 305.740 us; speedup vs baseline: 12.1014x; 1.4747x over previous
//
#include <hip/hip_runtime.h>
#include <hip/hip_bf16.h>

#define NN 100000
#define EE 800000
#define DALL 256
#define NEG 0.2f

typedef __attribute__((ext_vector_type(8))) short bf16x8;
typedef __attribute__((ext_vector_type(4))) float f32x4;

static __device__ __forceinline__ ushort f2b(float f) {
    __hip_bfloat16 h = __float2bfloat16(f);
    return *reinterpret_cast<ushort*>(&h);
}
static __device__ __forceinline__ float b2f(ushort u) {
    union { float f; unsigned v; } c; c.v = ((unsigned)u) << 16; return c.f;
}
static __device__ __forceinline__ void unpack8(uint4 u, float* v) {
    v[0] = b2f((ushort)(u.x & 0xffff)); v[1] = b2f((ushort)(u.x >> 16));
    v[2] = b2f((ushort)(u.y & 0xffff)); v[3] = b2f((ushort)(u.y >> 16));
    v[4] = b2f((ushort)(u.z & 0xffff)); v[5] = b2f((ushort)(u.z >> 16));
    v[6] = b2f((ushort)(u.w & 0xffff)); v[7] = b2f((ushort)(u.w >> 16));
}

// ---------------- convert x (fp32 -> bf16) ---------------------------------
__global__ __launch_bounds__(256) void cvt_x(const float* __restrict__ in,
                                             ushort* __restrict__ out)
{
    const int total = NN * DALL / 8;
    for (int i = blockIdx.x * 256 + threadIdx.x; i < total; i += gridDim.x * 256) {
        float4 a = reinterpret_cast<const float4*>(in)[i * 2];
        float4 b = reinterpret_cast<const float4*>(in)[i * 2 + 1];
        uint4 o;
        o.x = f2b(a.x) | ((unsigned)f2b(a.y) << 16);
        o.y = f2b(a.z) | ((unsigned)f2b(a.w) << 16);
        o.z = f2b(b.x) | ((unsigned)f2b(b.y) << 16);
        o.w = f2b(b.z) | ((unsigned)f2b(b.w) << 16);
        reinterpret_cast<uint4*>(out)[i] = o;
    }
}

// ------- build Wt[n][k] = bf16 of (n<256 ? Wl[k][n] : Wr[k][n-256]) --------
__global__ __launch_bounds__(256) void cvt_W(const float* __restrict__ Wl,
                                             const float* __restrict__ Wr,
                                             ushort* __restrict__ Wt)
{
    __shared__ float tile[32][33];
    int kt = blockIdx.x * 32, nt = blockIdx.y * 32;
    int tx = threadIdx.x & 31, ty = threadIdx.x >> 5;
#pragma unroll
    for (int i = 0; i < 32; i += 8) {
        int k = kt + ty + i, n = nt + tx;
        float v = (n < 256) ? Wl[(size_t)k * 256 + n] : Wr[(size_t)k * 256 + (n - 256)];
        tile[ty + i][tx] = v;
    }
    __syncthreads();
#pragma unroll
    for (int i = 0; i < 32; i += 8) {
        int n = nt + ty + i, k = kt + tx;
        Wt[(size_t)n * 256 + k] = f2b(tile[tx][ty + i]);
    }
}

// ------------- MFMA GEMM (m97 structure: global_load_lds + dbuf) -----------
// block: 128 rows x 128 cols, 4 waves (2x2), 64x64/wave, BK=32, linear LDS
__global__ __launch_bounds__(256) void gemm_dual(
    const ushort* __restrict__ xb,   // [NN][256] bf16
    const ushort* __restrict__ Wt,   // [512][256] bf16 (B^T layout)
    const float* __restrict__ bl, const float* __restrict__ br,
    ushort* __restrict__ xl, ushort* __restrict__ xr)
{
    __shared__ __align__(16) ushort smem[2][2][128 * 32]; // [buf][A,B][row*32]

    const int bx = blockIdx.x;
    const int rowBase = (bx >> 2) * 128;
    const int colBase = (bx & 3) * 128;
    const int t = threadIdx.x, lane = t & 63, wave = t >> 6;
    const int wr = (wave >> 1) * 64, wc = (wave & 1) * 64;

    const int sr  = lane >> 2;        // 0..15: row within a 16-row group
    const int sc8 = (lane & 3) * 8;   // element offset within 32-elem row

    f32x4 acc[4][4];
#pragma unroll
    for (int m = 0; m < 4; ++m)
#pragma unroll
        for (int n = 0; n < 4; ++n) acc[m][n] = (f32x4){0.f, 0.f, 0.f, 0.f};

    auto STAGE = [&](int buf, int kb) {
#pragma unroll
        for (int tt = 0; tt < 2; ++tt) {
            int rbase = wave * 32 + tt * 16;
            int r = rbase + sr;
            int ga = rowBase + r; if (ga >= NN) ga = NN - 1;
            const ushort* gpA = xb + (size_t)ga * 256 + kb + sc8;
            ushort* lpA = &smem[buf][0][rbase * 32];
            __builtin_amdgcn_global_load_lds(
                (const __attribute__((address_space(1))) unsigned int*)gpA,
                (__attribute__((address_space(3))) unsigned int*)lpA, 16, 0, 0);
            int gb = colBase + r;   // always < 512
            const ushort* gpB = Wt + (size_t)gb * 256 + kb + sc8;
            ushort* lpB = &smem[buf][1][rbase * 32];
            __builtin_amdgcn_global_load_lds(
                (const __attribute__((address_space(1))) unsigned int*)gpB,
                (__attribute__((address_space(3))) unsigned int*)lpB, 16, 0, 0);
        }
    };

    STAGE(0, 0);
    __syncthreads();

#pragma unroll
    for (int s = 0; s < 8; ++s) {
        if (s < 7) STAGE((s + 1) & 1, (s + 1) * 32);
        const ushort* A = smem[s & 1][0];
        const ushort* B = smem[s & 1][1];
        bf16x8 af[4], bfr[4];
#pragma unroll
        for (int m = 0; m < 4; ++m)
            af[m] = *reinterpret_cast<const bf16x8*>(
                &A[(wr + m * 16 + (lane & 15)) * 32 + (lane >> 4) * 8]);
#pragma unroll
        for (int n = 0; n < 4; ++n)
            bfr[n] = *reinterpret_cast<const bf16x8*>(
                &B[(wc + n * 16 + (lane & 15)) * 32 + (lane >> 4) * 8]);
#pragma unroll
        for (int m = 0; m < 4; ++m)
#pragma unroll
            for (int n = 0; n < 4; ++n)
                acc[m][n] = __builtin_amdgcn_mfma_f32_16x16x32_bf16(
                    af[m], bfr[n], acc[m][n], 0, 0, 0);
        if (s < 7) __syncthreads();
    }

    // epilogue
    const bool isL = (colBase < 256);
    ushort* OutP = isL ? xl : xr;
    const float* bvp = isL ? bl : br;
    const int cb0 = colBase & 255;

    int colLoc[4]; float bb[4];
#pragma unroll
    for (int n = 0; n < 4; ++n) {
        colLoc[n] = cb0 + wc + n * 16 + (lane & 15);
        bb[n] = bvp[colLoc[n]];
    }
#pragma unroll
    for (int m = 0; m < 4; ++m) {
        int r0 = rowBase + wr + m * 16 + (lane >> 4) * 4;
#pragma unroll
        for (int r = 0; r < 4; ++r) {
            int row = r0 + r;
            if (row < NN) {
#pragma unroll
                for (int n = 0; n < 4; ++n)
                    OutP[(size_t)row * 256 + colLoc[n]] = f2b(acc[m][n][r] + bb[n]);
            }
        }
    }
}

// ---------------- CSR build ------------------------------------------------
__global__ __launch_bounds__(256) void count_deg(const int* __restrict__ dst,
                                                 int* __restrict__ cnt)
{
    int e = blockIdx.x * 256 + threadIdx.x;
    if (e < EE) atomicAdd(&cnt[dst[e]], 1);
}

__global__ __launch_bounds__(256) void scan_part1(const int* __restrict__ cnt,
                                                  int* __restrict__ bsums)
{
    __shared__ int red[256];
    int base = blockIdx.x * 1024 + threadIdx.x * 4;
    int s = 0;
#pragma unroll
    for (int k = 0; k < 4; ++k) { int i = base + k; if (i < NN) s += cnt[i]; }
    red[threadIdx.x] = s; __syncthreads();
    for (int off = 128; off > 0; off >>= 1) {
        if (threadIdx.x < off) red[threadIdx.x] += red[threadIdx.x + off];
        __syncthreads();
    }
    if (threadIdx.x == 0) bsums[blockIdx.x] = red[0];
}

__global__ void scan_part2(int* bsums, int nb, int* rowptr)
{
    if (threadIdx.x == 0 && blockIdx.x == 0) {
        int run = 0;
        for (int i = 0; i < nb; ++i) { int v = bsums[i]; bsums[i] = run; run += v; }
        rowptr[NN] = run;
    }
}

__global__ __launch_bounds__(256) void scan_part3(const int* __restrict__ cnt,
                                                  const int* __restrict__ bsums,
                                                  int* __restrict__ rowptr)
{
    __shared__ int pre[256];
    int base = blockIdx.x * 1024 + threadIdx.x * 4;
    int v[4]; int s = 0;
#pragma unroll
    for (int k = 0; k < 4; ++k) { int i = base + k; v[k] = (i < NN) ? cnt[i] : 0; s += v[k]; }
    pre[threadIdx.x] = s; __syncthreads();
    for (int off = 1; off < 256; off <<= 1) {
        int tv = (threadIdx.x >= off) ? pre[threadIdx.x - off] : 0;
        __syncthreads();
        pre[threadIdx.x] += tv;
        __syncthreads();
    }
    int excl = pre[threadIdx.x] - s + bsums[blockIdx.x];
#pragma unroll
    for (int k = 0; k < 4; ++k) {
        int i = base + k;
        if (i < NN) { rowptr[i] = excl; excl += v[k]; }
    }
}

// stores SOURCE NODE IDS (not edge ids) in CSR order -> one less indirection
__global__ __launch_bounds__(256) void fill_csr(const int* __restrict__ src,
                                                const int* __restrict__ dst,
                                                const int* __restrict__ rowptr,
                                                int* __restrict__ cursor,
                                                int* __restrict__ srcs)
{
    int e = blockIdx.x * 256 + threadIdx.x;
    if (e >= EE) return;
    int d = dst[e];
    int pos = atomicAdd(&cursor[d], 1);
    srcs[rowptr[d] + pos] = src[e];
}

// ------------- fused: score + softmax-agg + bias + residual + LN + ELU -----
// one wave per node; 2 edges/wave (32 lanes each, 8 dims/lane), unroll x2
__global__ __launch_bounds__(256) void aggregate_finalize(
    const ushort* __restrict__ xl, const ushort* __restrict__ xr,
    const int* __restrict__ srcs, const int* __restrict__ rowptr,
    const float* __restrict__ att, const ushort* __restrict__ xb,
    const float* __restrict__ bias, const float* __restrict__ gamma,
    const float* __restrict__ beta, float* __restrict__ out)
{
    int node = blockIdx.x * 4 + (threadIdx.x >> 6);
    if (node >= NN) return;
    int lane = threadIdx.x & 63;
    int half = lane >> 5;
    int dl = lane & 31;          // dims [dl*8, dl*8+8), head = dl>>2
    const int off = dl * 8;

    uint4 xru = *reinterpret_cast<const uint4*>(xr + (size_t)node * DALL + off);
    float xrv[8]; unpack8(xru, xrv);
    float atv[8];
    {
        float4 a0 = *reinterpret_cast<const float4*>(att + off);
        float4 a1 = *reinterpret_cast<const float4*>(att + off + 4);
        atv[0]=a0.x; atv[1]=a0.y; atv[2]=a0.z; atv[3]=a0.w;
        atv[4]=a1.x; atv[5]=a1.y; atv[6]=a1.z; atv[7]=a1.w;
    }

    int beg = rowptr[node], end = rowptr[node + 1];
    float a[8] = {0.f,0.f,0.f,0.f,0.f,0.f,0.f,0.f};
    float dsum = 0.f;

    for (int base = beg; base < end; base += 4) {
        int jA = base + half;
        int jB = base + 2 + half;
        bool vA = jA < end, vB = jB < end;
        int sA = srcs[vA ? jA : beg];
        int sB = srcs[vB ? jB : beg];
        uint4 gA = *reinterpret_cast<const uint4*>(xl + (size_t)sA * DALL + off);
        uint4 gB = *reinterpret_cast<const uint4*>(xl + (size_t)sB * DALL + off);
        float vAv[8], vBv[8]; unpack8(gA, vAv); unpack8(gB, vBv);
        float pA = 0.f, pB = 0.f;
#pragma unroll
        for (int i = 0; i < 8; ++i) {
            float z = vAv[i] + xrv[i];
            z = fmaxf(z, 0.f) + NEG * fminf(z, 0.f);
            pA += z * atv[i];
            float z2 = vBv[i] + xrv[i];
            z2 = fmaxf(z2, 0.f) + NEG * fminf(z2, 0.f);
            pB += z2 * atv[i];
        }
        pA += __shfl_xor(pA, 1); pA += __shfl_xor(pA, 2);   // 4-lane head group
        pB += __shfl_xor(pB, 1); pB += __shfl_xor(pB, 2);
        float peA = vA ? __expf(pA) : 0.f;
        float peB = vB ? __expf(pB) : 0.f;
#pragma unroll
        for (int i = 0; i < 8; ++i) a[i] += peA * vAv[i] + peB * vBv[i];
        dsum += peA + peB;
    }

    // merge the two half-wave partial sums
#pragma unroll
    for (int i = 0; i < 8; ++i) a[i] += __shfl_xor(a[i], 32);
    dsum += __shfl_xor(dsum, 32);
    float inv = dsum > 0.f ? 1.f / dsum : 0.f;

    uint4 xbu = *reinterpret_cast<const uint4*>(xb + (size_t)node * DALL + off);
    float xv[8]; unpack8(xbu, xv);
    float bvv[8], gvv[8], bev[8];
    {
        float4 b0 = *reinterpret_cast<const float4*>(bias + off);
        float4 b1 = *reinterpret_cast<const float4*>(bias + off + 4);
        bvv[0]=b0.x; bvv[1]=b0.y; bvv[2]=b0.z; bvv[3]=b0.w;
        bvv[4]=b1.x; bvv[5]=b1.y; bvv[6]=b1.z; bvv[7]=b1.w;
        float4 g0 = *reinterpret_cast<const float4*>(gamma + off);
        float4 g1 = *reinterpret_cast<const float4*>(gamma + off + 4);
        gvv[0]=g0.x; gvv[1]=g0.y; gvv[2]=g0.z; gvv[3]=g0.w;
        gvv[4]=g1.x; gvv[5]=g1.y; gvv[6]=g1.z; gvv[7]=g1.w;
        float4 e0 = *reinterpret_cast<const float4*>(beta + off);
        float4 e1 = *reinterpret_cast<const float4*>(beta + off + 4);
        bev[0]=e0.x; bev[1]=e0.y; bev[2]=e0.z; bev[3]=e0.w;
        bev[4]=e1.x; bev[5]=e1.y; bev[6]=e1.z; bev[7]=e1.w;
    }

    float y[8]; float sum = 0.f, sq = 0.f;
#pragma unroll
    for (int i = 0; i < 8; ++i) {
        y[i] = a[i] * inv + bvv[i] + xv[i];
        sum += y[i]; sq += y[i] * y[i];
    }
#pragma unroll
    for (int m = 1; m < 32; m <<= 1) {
        sum += __shfl_xor(sum, m);
        sq  += __shfl_xor(sq, m);
    }
    float mu  = sum * (1.0f / 256.0f);
    float var = sq * (1.0f / 256.0f) - mu * mu;
    float rr  = rsqrtf(var + 1e-5f);

    if (half == 0) {
        float4 o0, o1;
        float z0 = (y[0]-mu)*rr*gvv[0] + bev[0];
        float z1 = (y[1]-mu)*rr*gvv[1] + bev[1];
        float z2 = (y[2]-mu)*rr*gvv[2] + bev[2];
        float z3 = (y[3]-mu)*rr*gvv[3] + bev[3];
        float z4 = (y[4]-mu)*rr*gvv[4] + bev[4];
        float z5 = (y[5]-mu)*rr*gvv[5] + bev[5];
        float z6 = (y[6]-mu)*rr*gvv[6] + bev[6];
        float z7 = (y[7]-mu)*rr*gvv[7] + bev[7];
        o0.x = z0 > 0.f ? z0 : expm1f(z0);
        o0.y = z1 > 0.f ? z1 : expm1f(z1);
        o0.z = z2 > 0.f ? z2 : expm1f(z2);
        o0.w = z3 > 0.f ? z3 : expm1f(z3);
        o1.x = z4 > 0.f ? z4 : expm1f(z4);
        o1.y = z5 > 0.f ? z5 : expm1f(z5);
        o1.z = z6 > 0.f ? z6 : expm1f(z6);
        o1.w = z7 > 0.f ? z7 : expm1f(z7);
        *reinterpret_cast<float4*>(out + (size_t)node * DALL + off)     = o0;
        *reinterpret_cast<float4*>(out + (size_t)node * DALL + off + 4) = o1;
    }
}

extern "C" void kernel_launch(void* const* d_in, const int* in_sizes, int n_in,
                              void* d_out, int out_size, void* d_ws, size_t ws_size,
                              hipStream_t stream)
{
    const float* x    = (const float*)d_in[0];
    const int*   edge = (const int*)d_in[1];
    const float* Wl   = (const float*)d_in[2];
    const float* bl   = (const float*)d_in[3];
    const float* Wr   = (const float*)d_in[4];
    const float* br   = (const float*)d_in[5];
    const float* att  = (const float*)d_in[6];
    const float* bias = (const float*)d_in[7];
    const float* gamma= (const float*)d_in[8];
    const float* beta = (const float*)d_in[9];
    float* out = (float*)d_out;

    const int* srcIdx = edge;
    const int* dstIdx = edge + EE;

    ushort* xl = (ushort*)d_ws;                     // NN*256 bf16
    ushort* xr = xl + (size_t)NN * DALL;            // NN*256 bf16
    ushort* xb = xr + (size_t)NN * DALL;            // NN*256 bf16
    ushort* Wt = xb + (size_t)NN * DALL;            // 512*256 bf16
    int* rowptr = (int*)(Wt + 512 * 256);           // NN+1
    int* cursor = rowptr + NN + 1;                  // NN
    int* srcs   = cursor + NN;                      // EE
    int* bsums  = srcs + EE;                        // 128

    const int SCAN_NB = (NN + 1023) / 1024;

    cvt_x<<<2048, 256, 0, stream>>>(x, xb);
    cvt_W<<<dim3(8, 16), 256, 0, stream>>>(Wl, Wr, Wt);
    gemm_dual<<<782 * 4, 256, 0, stream>>>(xb, Wt, bl, br, xl, xr);

    hipMemsetAsync(cursor, 0, NN * sizeof(int), stream);
    count_deg<<<(EE + 255) / 256, 256, 0, stream>>>(dstIdx, cursor);
    scan_part1<<<SCAN_NB, 256, 0, stream>>>(cursor, bsums);
    scan_part2<<<1, 64, 0, stream>>>(bsums, SCAN_NB, rowptr);
    scan_part3<<<SCAN_NB, 256, 0, stream>>>(cursor, bsums, rowptr);
    hipMemsetAsync(cursor, 0, NN * sizeof(int), stream);
    fill_csr<<<(EE + 255) / 256, 256, 0, stream>>>(srcIdx, dstIdx, rowptr, cursor, srcs);

    aggregate_finalize<<<NN / 4, 256, 0, stream>>>(
        xl, xr, srcs, rowptr, att, xb, bias, gamma, beta, out);
}